// Round 4
// baseline (233.476 us; speedup 1.0000x reference)
//
#include <hip/hip_runtime.h>
#include <math.h>

#define NPIX 4096
#define CH   256
#define CQD  32
#define LOG2E 1.44269504088896340736f

typedef float f32x4 __attribute__((ext_vector_type(4)));
typedef short s16x8 __attribute__((ext_vector_type(8)));

__device__ __forceinline__ unsigned short f2bf(float f) {
  unsigned u = __builtin_bit_cast(unsigned, f);
  return (unsigned short)((u + 0x7FFFu + ((u >> 16) & 1u)) >> 16);
}

__device__ __forceinline__ f32x4 mfma16(s16x8 a, s16x8 b, f32x4 c) {
  return __builtin_amdgcn_mfma_f32_16x16x32_bf16(a, b, c, 0, 0, 0);
}

__device__ __forceinline__ float fexp2(float x) {
#if __has_builtin(__builtin_amdgcn_exp2f)
  return __builtin_amdgcn_exp2f(x);
#else
  return exp2f(x);
#endif
}

__device__ __forceinline__ float frcp(float x) {
#if __has_builtin(__builtin_amdgcn_rcpf)
  return __builtin_amdgcn_rcpf(x);
#else
  return 1.0f / x;
#endif
}

// ---------------- Weight prepack: f32 -> bf16, wq scaled by log2e ----------------
// Wp rows: [0,32) = wq*log2e, [32,64) = wk, [64,320) = wv.  Layout [row][256].
__global__ __launch_bounds__(256) void wpack_kernel(
    const float* __restrict__ wq, const float* __restrict__ wk,
    const float* __restrict__ wv, unsigned short* __restrict__ Wp)
{
  const int row = blockIdx.x;
  const int c = threadIdx.x;
  float v;
  if (row < 32)      v = wq[row * CH + c] * LOG2E;
  else if (row < 64) v = wk[(row - 32) * CH + c];
  else               v = wv[(row - 64) * CH + c];
  Wp[(size_t)row * CH + c] = f2bf(v);
}

// ---------------- x transpose: x[b][c][px] f32 -> Xt[b][px][c] bf16 ----------------
// grid 1024 = b(4) x ct(4) x pt(64); 64c x 64px tile via conflict-free LDS.
__global__ __launch_bounds__(256) void xt_kernel(
    const float* __restrict__ x, unsigned short* __restrict__ Xt)
{
  __shared__ float Lf[64][65];   // row stride 65 words -> all LDS ops exactly 2-way (free)

  const int blk = blockIdx.x;
  const int pt = blk & 63;
  const int ct = (blk >> 6) & 3;
  const int b  = blk >> 8;
  const int t = threadIdx.x;

  // load: lanes along px (coalesced 256B per c-row)
  {
    const int px4 = (t & 15) * 4;
    const int cl  = t >> 4;      // 0..15
    const float* xb = x + ((size_t)b * CH + ct * 64) * NPIX + (size_t)pt * 64;
    #pragma unroll
    for (int it = 0; it < 4; ++it) {
      const int c = cl + it * 16;
      const float4 v = *(const float4*)&xb[(size_t)c * NPIX + px4];
      Lf[c][px4 + 0] = v.x;
      Lf[c][px4 + 1] = v.y;
      Lf[c][px4 + 2] = v.z;
      Lf[c][px4 + 3] = v.w;
    }
  }
  __syncthreads();

  // store: lanes along c (128B contiguous per px-row)
  {
    const int c4 = (t & 15) * 4;
    const int pl = t >> 4;       // 0..15
    unsigned short* xtb = Xt + ((size_t)b * NPIX + (size_t)pt * 64) * CH + ct * 64;
    #pragma unroll
    for (int it = 0; it < 4; ++it) {
      const int px = pl + it * 16;
      ushort4 pk;
      pk.x = f2bf(Lf[c4 + 0][px]);
      pk.y = f2bf(Lf[c4 + 1][px]);
      pk.z = f2bf(Lf[c4 + 2][px]);
      pk.w = f2bf(Lf[c4 + 3][px]);
      *(ushort4*)&xtb[(size_t)px * CH + c4] = pk;
    }
  }
}

// ---------------- Projection: pure-register GEMM, no LDS, no barriers ----------------
// grid 1024: b = blk>>8, pt = blk&255 (16-pixel tile). Wave w computes d-tiles
// dt = {w, 4+w, 8+w, 12+w, 16+w}: dt<2 -> Q, dt<4 -> K (mfma(W,X): D rows=ch, cols=px),
// dt>=4 -> V (mfma(X,W): D rows=px, cols=ch) so both store layouts are ushort4.
__global__ __launch_bounds__(256, 4) void proj_kernel(
    const unsigned short* __restrict__ Xt, const unsigned short* __restrict__ Wp,
    const float* __restrict__ bq, const float* __restrict__ bk,
    const float* __restrict__ bv,
    unsigned short* __restrict__ Qb, unsigned short* __restrict__ Kb,
    unsigned short* __restrict__ Vb)
{
  const int blk = blockIdx.x;
  const int pt = blk & 255;
  const int b  = blk >> 8;
  const int tid = threadIdx.x;
  const int w = tid >> 6;
  const int lane = tid & 63;
  const int g = lane >> 4;
  const int r = lane & 15;

  // X fragments: lane r -> pixel pt*16+r, k-slices of 8 channels (reused by all 5 dt)
  const unsigned short* xtp = Xt + ((size_t)b * NPIX + pt * 16 + r) * CH + g * 8;
  s16x8 xf[8];
  #pragma unroll
  for (int kt = 0; kt < 8; ++kt) xf[kt] = *(const s16x8*)&xtp[kt * 32];

  f32x4 acc[5];
  #pragma unroll
  for (int dd = 0; dd < 5; ++dd) { acc[dd][0]=0.f; acc[dd][1]=0.f; acc[dd][2]=0.f; acc[dd][3]=0.f; }

  #pragma unroll
  for (int dd = 0; dd < 5; ++dd) {
    const int dt = dd * 4 + w;
    const unsigned short* wp = Wp + (size_t)(dt * 16 + r) * CH + g * 8;
    if (dd == 0) {
      #pragma unroll
      for (int kt = 0; kt < 8; ++kt) {
        const s16x8 wf = *(const s16x8*)&wp[kt * 32];
        acc[0] = mfma16(wf, xf[kt], acc[0]);     // D rows=ch, cols=px
      }
    } else {
      #pragma unroll
      for (int kt = 0; kt < 8; ++kt) {
        const s16x8 wf = *(const s16x8*)&wp[kt * 32];
        acc[dd] = mfma16(xf[kt], wf, acc[dd]);   // D rows=px, cols=ch
      }
    }
  }

  // Q/K store (dd==0): lane (g,r): px=r, ch = dloc+g*4+e
  {
    const int dt = w;
    const int dloc = (dt & 1) * 16;
    const float* bp = (dt < 2) ? bq : bk;
    float4 bias = *(const float4*)&bp[dloc + g * 4];
    if (dt < 2) { bias.x *= LOG2E; bias.y *= LOG2E; bias.z *= LOG2E; bias.w *= LOG2E; }
    unsigned short* dst = (dt < 2) ? Qb : Kb;
    ushort4 pk;
    pk.x = f2bf(acc[0][0] + bias.x);
    pk.y = f2bf(acc[0][1] + bias.y);
    pk.z = f2bf(acc[0][2] + bias.z);
    pk.w = f2bf(acc[0][3] + bias.w);
    *(ushort4*)&dst[((size_t)b * NPIX + pt * 16 + r) * CQD + dloc + g * 4] = pk;
  }

  // V stores (dd=1..4): lane (g,r): ch=(dt-4)*16+r, px = pt*16+g*4+e
  #pragma unroll
  for (int dd = 1; dd < 5; ++dd) {
    const int dt = dd * 4 + w;
    const int vch = (dt - 4) * 16 + r;
    const float bias = bv[vch];
    ushort4 pk;
    pk.x = f2bf(acc[dd][0] + bias);
    pk.y = f2bf(acc[dd][1] + bias);
    pk.z = f2bf(acc[dd][2] + bias);
    pk.w = f2bf(acc[dd][3] + bias);
    *(ushort4*)&Vb[((size_t)b * CH + vch) * NPIX + pt * 16 + g * 4] = pk;
  }
}

// ---------------- Flash attention + residual ----------------
// grid 1024: xcd=blk&7 -> b=xcd>>1, s_lo=xcd&1; s_hi=(blk>>3)&1; i0=(blk>>4)*64.
// 4 channel-splits of 64 ch; wave w owns softmax rows w*16..+16 and 16 V-channels
// c0 = split*64 + w*16.  No-max softmax: P = exp2(S), Q pre-scaled by log2e.
// Row-sum l via ones-MFMA on wave 3.  One barrier/tile, double-buffered P in LDS.
__global__ __launch_bounds__(256, 4) void attn_kernel(
    const unsigned short* __restrict__ Qb, const unsigned short* __restrict__ Kb,
    const unsigned short* __restrict__ Vb, const float* __restrict__ x,
    const float* __restrict__ gamma, float* __restrict__ out)
{
  __shared__ __align__(16) unsigned char smem[2 * 64 * 88 * 2];  // 22528 B
  __shared__ float l_s[64];

  typedef unsigned short PsArr[64][88];
  PsArr* Ps = (PsArr*)smem;

  const int blk = blockIdx.x;
  const int xcd = blk & 7;
  const int b = xcd >> 1;
  const int split = ((blk >> 3) & 1) * 2 + (xcd & 1);
  const int i0 = (blk >> 4) * 64;

  const int tid = threadIdx.x;
  const int w = tid >> 6;
  const int lane = tid & 63;
  const int g = lane >> 4;
  const int r = lane & 15;
  const int c0 = split * 64 + w * 16;

  const unsigned short* __restrict__ Qbase = Qb + (size_t)b * NPIX * CQD;
  const unsigned short* __restrict__ Kbase = Kb + (size_t)b * NPIX * CQD;
  const unsigned short* __restrict__ Vbase = Vb + (size_t)b * CH * NPIX;

  const s16x8 qf = *(const s16x8*)&Qbase[(size_t)(i0 + w * 16 + r) * CQD + g * 8];

  s16x8 ones;
  #pragma unroll
  for (int j = 0; j < 8; ++j) ones[j] = (short)0x3F80;  // bf16 1.0

  f32x4 o[4];
  f32x4 o_l[4];
  #pragma unroll
  for (int is = 0; is < 4; ++is) {
    o[is][0]=0.f; o[is][1]=0.f; o[is][2]=0.f; o[is][3]=0.f;
    o_l[is][0]=0.f; o_l[is][1]=0.f; o_l[is][2]=0.f; o_l[is][3]=0.f;
  }

  // prefetch tile 0
  s16x8 kf0 = *(const s16x8*)&Kbase[(size_t)( 0 + r) * CQD + g * 8];
  s16x8 kf1 = *(const s16x8*)&Kbase[(size_t)(16 + r) * CQD + g * 8];
  s16x8 kf2 = *(const s16x8*)&Kbase[(size_t)(32 + r) * CQD + g * 8];
  s16x8 kf3 = *(const s16x8*)&Kbase[(size_t)(48 + r) * CQD + g * 8];
  const unsigned short* vp = Vbase + (size_t)(c0 + r) * NPIX + g * 8;
  s16x8 vf0 = *(const s16x8*)vp;
  s16x8 vf1 = *(const s16x8*)(vp + 32);

  #pragma unroll 1
  for (int t = 0; t < 64; ++t) {
    const int cur = t & 1;
    const f32x4 z = {0.f, 0.f, 0.f, 0.f};
    f32x4 s0 = mfma16(qf, kf0, z);
    f32x4 s1 = mfma16(qf, kf1, z);
    f32x4 s2 = mfma16(qf, kf2, z);
    f32x4 s3 = mfma16(qf, kf3, z);

    // prefetch next tile (stays in flight across the barrier)
    const int jn = ((t + 1) & 63) * 64;
    const s16x8 nkf0 = *(const s16x8*)&Kbase[(size_t)(jn +  0 + r) * CQD + g * 8];
    const s16x8 nkf1 = *(const s16x8*)&Kbase[(size_t)(jn + 16 + r) * CQD + g * 8];
    const s16x8 nkf2 = *(const s16x8*)&Kbase[(size_t)(jn + 32 + r) * CQD + g * 8];
    const s16x8 nkf3 = *(const s16x8*)&Kbase[(size_t)(jn + 48 + r) * CQD + g * 8];
    const unsigned short* nvp = Vbase + (size_t)(c0 + r) * NPIX + jn + g * 8;
    const s16x8 nvf0 = *(const s16x8*)nvp;
    const s16x8 nvf1 = *(const s16x8*)(nvp + 32);

    // P = exp2(S) -> bf16 -> LDS
    #pragma unroll
    for (int e = 0; e < 4; ++e) {
      const int row = w * 16 + g * 4 + e;
      Ps[cur][row][ 0 + r] = f2bf(fexp2(s0[e]));
      Ps[cur][row][16 + r] = f2bf(fexp2(s1[e]));
      Ps[cur][row][32 + r] = f2bf(fexp2(s2[e]));
      Ps[cur][row][48 + r] = f2bf(fexp2(s3[e]));
    }

    __syncthreads();

    #pragma unroll
    for (int is = 0; is < 4; ++is) {
      const s16x8 pf0 = *(const s16x8*)&Ps[cur][is * 16 + r][ 0 + g * 8];
      const s16x8 pf1 = *(const s16x8*)&Ps[cur][is * 16 + r][32 + g * 8];
      o[is] = mfma16(pf0, vf0, o[is]);
      o[is] = mfma16(pf1, vf1, o[is]);
      if (w == 3) {
        o_l[is] = mfma16(pf0, ones, o_l[is]);
        o_l[is] = mfma16(pf1, ones, o_l[is]);
      }
    }

    kf0 = nkf0; kf1 = nkf1; kf2 = nkf2; kf3 = nkf3;
    vf0 = nvf0; vf1 = nvf1;
  }

  // l to LDS (wave 3 holds row sums; all D-cols equal, take r==0 lanes)
  if (w == 3 && r == 0) {
    #pragma unroll
    for (int is = 0; is < 4; ++is)
      #pragma unroll
      for (int e = 0; e < 4; ++e)
        l_s[is * 16 + g * 4 + e] = o_l[is][e];
  }
  __syncthreads();  // orders last PV reads + l_s write before smem reuse

  // per-wave transpose into smem-as-float (64 x 17 f32 per wave = 17408 B total)
  float* otp = ((float*)smem) + (size_t)w * (64 * 17);
  #pragma unroll
  for (int is = 0; is < 4; ++is) {
    #pragma unroll
    for (int e = 0; e < 4; ++e) {
      const int row = is * 16 + g * 4 + e;
      otp[row * 17 + r] = o[is][e] * frcp(l_s[row]);
    }
  }

  const float gam = gamma[0];
  const size_t obase = ((size_t)b * CH + c0) * NPIX + i0 + lane;
  #pragma unroll 1
  for (int cl = 0; cl < 16; ++cl) {
    const size_t off = obase + (size_t)cl * NPIX;
    out[off] = gam * otp[lane * 17 + cl] + x[off];
  }
}

extern "C" void kernel_launch(void* const* d_in, const int* in_sizes, int n_in,
                              void* d_out, int out_size, void* d_ws, size_t ws_size,
                              hipStream_t stream) {
  const float* x     = (const float*)d_in[0];
  const float* wq    = (const float*)d_in[1];
  const float* bq    = (const float*)d_in[2];
  const float* wk    = (const float*)d_in[3];
  const float* bk    = (const float*)d_in[4];
  const float* wv    = (const float*)d_in[5];
  const float* bv    = (const float*)d_in[6];
  const float* gamma = (const float*)d_in[7];
  float* out = (float*)d_out;

  unsigned short* Qb = (unsigned short*)d_ws;                 // 4*4096*32  = 1 MB
  unsigned short* Kb = Qb + (size_t)4 * NPIX * CQD;           // 1 MB
  unsigned short* Vb = Kb + (size_t)4 * NPIX * CQD;           // 4*256*4096 = 8 MB
  unsigned short* Wp = Vb + (size_t)4 * CH * NPIX;            // 320*256    = 160 KB
  unsigned short* Xt = Wp + (size_t)320 * CH;                 // 4*4096*256 = 8 MB

  hipLaunchKernelGGL(wpack_kernel, dim3(320), dim3(256), 0, stream, wq, wk, wv, Wp);
  hipLaunchKernelGGL(xt_kernel,   dim3(1024), dim3(256), 0, stream, x, Xt);
  hipLaunchKernelGGL(proj_kernel, dim3(1024), dim3(256), 0, stream,
                     Xt, Wp, bq, bk, bv, Qb, Kb, Vb);
  hipLaunchKernelGGL(attn_kernel, dim3(1024), dim3(256), 0, stream,
                     Qb, Kb, Vb, x, gamma, out);
}

// Round 6
// 165.807 us; speedup vs baseline: 1.4081x; 1.4081x over previous
//
#include <hip/hip_runtime.h>
#include <math.h>

#define NPIX 4096
#define CH   256
#define CQD  32
#define LOG2E 1.44269504088896340736f

typedef float f32x4 __attribute__((ext_vector_type(4)));
typedef short s16x8 __attribute__((ext_vector_type(8)));

__device__ __forceinline__ unsigned short f2bf(float f) {
  unsigned u = __builtin_bit_cast(unsigned, f);
  return (unsigned short)((u + 0x7FFFu + ((u >> 16) & 1u)) >> 16);
}

// v_cvt_pk_bf16_f32: D[15:0]=bf16(a), D[31:16]=bf16(b)  (no builtin on gfx950)
__device__ __forceinline__ unsigned cvt_pk_bf16(float a, float b) {
  unsigned d;
  asm("v_cvt_pk_bf16_f32 %0, %1, %2" : "=v"(d) : "v"(a), "v"(b));
  return d;
}

__device__ __forceinline__ f32x4 mfma16(s16x8 a, s16x8 b, f32x4 c) {
  return __builtin_amdgcn_mfma_f32_16x16x32_bf16(a, b, c, 0, 0, 0);
}

__device__ __forceinline__ float fexp2(float x) {
#if __has_builtin(__builtin_amdgcn_exp2f)
  return __builtin_amdgcn_exp2f(x);
#else
  return exp2f(x);
#endif
}

__device__ __forceinline__ float frcp(float x) {
#if __has_builtin(__builtin_amdgcn_rcpf)
  return __builtin_amdgcn_rcpf(x);
#else
  return 1.0f / x;
#endif
}

// ---------------- wpack: W -> bf16 rows [0,32)=wq*log2e [32,64)=wk [64,320)=wv ----------------
__global__ __launch_bounds__(256) void wpack_kernel(
    const float* __restrict__ wq, const float* __restrict__ wk,
    const float* __restrict__ wv, unsigned short* __restrict__ Wp)
{
  const int row = blockIdx.x;
  const int c = threadIdx.x;
  float v;
  if (row < 32)      v = wq[row * CH + c] * LOG2E;
  else if (row < 64) v = wk[(row - 32) * CH + c];
  else               v = wv[(row - 64) * CH + c];
  Wp[(size_t)row * CH + c] = f2bf(v);
}

// ---------------- Projection: grid 256 (b, 64-px tile), 512 threads ----------------
// Stage x[b][:, p0..p0+63] -> Xs[px][c] bf16 (coalesced loads, b64 LDS writes).
// Wave w owns d-tiles {w, 8+w} (+{16+w} if w<4), 16 out-ch each.
// dt<4 (Q/K): acc = mfma(X_A, W_B) -> D rows=px, cols=ch -> [px][ch] stores.
// dt>=4 (V) : acc = mfma(W_A, X_B) -> D rows=ch, cols=px -> [ch][px] stores.
__global__ __launch_bounds__(512, 2) void proj_kernel(
    const float* __restrict__ x, const unsigned short* __restrict__ Wp,
    const float* __restrict__ bq, const float* __restrict__ bk,
    const float* __restrict__ bv,
    unsigned short* __restrict__ Qb, unsigned short* __restrict__ Kb,
    unsigned short* __restrict__ Vb)
{
  __shared__ unsigned short Xs[64][264];   // 33792 B; 528B rows (16B-mult)

  const int blk = blockIdx.x;
  const int b  = blk >> 6;
  const int p0 = (blk & 63) * 64;
  const int t = threadIdx.x;
  const int w = t >> 6;
  const int lane = t & 63;
  const int g = lane >> 4;
  const int r = lane & 15;

  // stage: thread t loads px = t&63, channel-quad (t>>6)*4 + 32*it
  {
    const int px = t & 63;
    const int cb = (t >> 6) * 4;
    const float* xb = x + (size_t)b * CH * NPIX + p0 + px;
    #pragma unroll
    for (int it = 0; it < 8; ++it) {
      const int c = cb + it * 32;
      const float f0 = xb[(size_t)(c + 0) * NPIX];
      const float f1 = xb[(size_t)(c + 1) * NPIX];
      const float f2 = xb[(size_t)(c + 2) * NPIX];
      const float f3 = xb[(size_t)(c + 3) * NPIX];
      uint2 pk;
      pk.x = cvt_pk_bf16(f0, f1);
      pk.y = cvt_pk_bf16(f2, f3);
      *(uint2*)&Xs[px][c] = pk;
    }
  }
  __syncthreads();

  const int ndd = (w < 4) ? 3 : 2;

  f32x4 acc[3][4];
  #pragma unroll
  for (int dd = 0; dd < 3; ++dd)
    #pragma unroll
    for (int ps = 0; ps < 4; ++ps) { acc[dd][ps][0]=0.f; acc[dd][ps][1]=0.f; acc[dd][ps][2]=0.f; acc[dd][ps][3]=0.f; }

  #pragma unroll
  for (int kt = 0; kt < 8; ++kt) {
    s16x8 xf[4];
    #pragma unroll
    for (int ps = 0; ps < 4; ++ps)
      xf[ps] = *(const s16x8*)&Xs[ps * 16 + r][kt * 32 + g * 8];
    #pragma unroll
    for (int dd = 0; dd < 3; ++dd) {
      if (dd >= ndd) continue;
      const int dt = w + dd * 8;
      const s16x8 wf = *(const s16x8*)&Wp[(size_t)(dt * 16 + r) * CH + kt * 32 + g * 8];
      if (dt < 4) {
        #pragma unroll
        for (int ps = 0; ps < 4; ++ps) acc[dd][ps] = mfma16(xf[ps], wf, acc[dd][ps]);
      } else {
        #pragma unroll
        for (int ps = 0; ps < 4; ++ps) acc[dd][ps] = mfma16(wf, xf[ps], acc[dd][ps]);
      }
    }
  }

  #pragma unroll
  for (int dd = 0; dd < 3; ++dd) {
    if (dd >= ndd) continue;
    const int dt = w + dd * 8;
    if (dt < 4) {
      // Q/K: lane (g,r), elem e: px = p0+ps*16+4g+e, out-ch = dloc + r
      const int dloc = (dt & 1) * 16;
      float bias = (dt < 2) ? bq[dloc + r] * LOG2E : bk[dloc + r];
      unsigned short* dst = (dt < 2) ? Qb : Kb;
      #pragma unroll
      for (int ps = 0; ps < 4; ++ps)
        #pragma unroll
        for (int e = 0; e < 4; ++e) {
          const int px = p0 + ps * 16 + 4 * g + e;
          dst[((size_t)b * NPIX + px) * CQD + dloc + r] = f2bf(acc[dd][ps][e] + bias);
        }
    } else {
      // V: lane (g,r), elem e: ch = (dt-4)*16+4g+e, px = p0+ps*16+r
      const int c0v = (dt - 4) * 16;
      const float4 b4 = *(const float4*)&bv[c0v + 4 * g];
      #pragma unroll
      for (int ps = 0; ps < 4; ++ps) {
        const int px = p0 + ps * 16 + r;
        Vb[((size_t)b * CH + c0v + 4 * g + 0) * NPIX + px] = f2bf(acc[dd][ps][0] + b4.x);
        Vb[((size_t)b * CH + c0v + 4 * g + 1) * NPIX + px] = f2bf(acc[dd][ps][1] + b4.y);
        Vb[((size_t)b * CH + c0v + 4 * g + 2) * NPIX + px] = f2bf(acc[dd][ps][2] + b4.z);
        Vb[((size_t)b * CH + c0v + 4 * g + 3) * NPIX + px] = f2bf(acc[dd][ps][3] + b4.w);
      }
    }
  }
}

// ---------------- Flash attention + residual ----------------
// grid 512: xcd=blk&7 -> b=xcd>>1, split=xcd&1; i0=(blk>>3)*64 (QBLK=64).
// Wave w: QK for j-sub w*16 (swapped: mfma(K,Q), D rows=j cols=i) -> lane holds
// 4 consecutive j per i-sub -> cvt_pk -> ONE b64 LDS write per i-sub.
// PV swapped: mfma(V,P) -> D rows=ch cols=i -> direct coalesced epilogue.
// l via ones-MFMA (wave w accumulates l for i-sub w). One barrier/tile, dbuf P.
__global__ __launch_bounds__(256, 2) void attn_kernel(
    const unsigned short* __restrict__ Qb, const unsigned short* __restrict__ Kb,
    const unsigned short* __restrict__ Vb, const float* __restrict__ x,
    const float* __restrict__ gamma, float* __restrict__ out)
{
  __shared__ __align__(16) unsigned short Ps[2][64][72];  // 18432 B (144B rows)
  __shared__ float l_s[64];

  const int blk = blockIdx.x;
  const int xcd = blk & 7;
  const int b = xcd >> 1;
  const int split = xcd & 1;
  const int i0 = (blk >> 3) * 64;

  const int tid = threadIdx.x;
  const int w = tid >> 6;
  const int lane = tid & 63;
  const int g = lane >> 4;
  const int r = lane & 15;
  const int c0 = split * 128 + w * 32;

  const unsigned short* __restrict__ Qbase = Qb + (size_t)b * NPIX * CQD;
  const unsigned short* __restrict__ Kbase = Kb + (size_t)b * NPIX * CQD;
  const unsigned short* __restrict__ Vbase = Vb + (size_t)b * CH * NPIX;

  // Q B-frags: lane r = i-col, 4 i-subs (hoisted for all tiles)
  s16x8 qf[4];
  #pragma unroll
  for (int is = 0; is < 4; ++is)
    qf[is] = *(const s16x8*)&Qbase[(size_t)(i0 + is * 16 + r) * CQD + g * 8];

  s16x8 ones;
  #pragma unroll
  for (int j = 0; j < 8; ++j) ones[j] = (short)0x3F80;  // bf16 1.0

  f32x4 o[4][2];   // [i-sub][ch-sub]
  f32x4 o_l = {0.f, 0.f, 0.f, 0.f};
  #pragma unroll
  for (int is = 0; is < 4; ++is)
    #pragma unroll
    for (int cs = 0; cs < 2; ++cs) { o[is][cs][0]=0.f; o[is][cs][1]=0.f; o[is][cs][2]=0.f; o[is][cs][3]=0.f; }

  // tile-0 prefetch: K A-frag (wave's 16-j sub), V A-frags (2 ch-sub x 2 k-sub)
  s16x8 kf = *(const s16x8*)&Kbase[(size_t)(w * 16 + r) * CQD + g * 8];
  s16x8 vf[2][2];
  #pragma unroll
  for (int cs = 0; cs < 2; ++cs)
    #pragma unroll
    for (int ks = 0; ks < 2; ++ks)
      vf[cs][ks] = *(const s16x8*)&Vbase[(size_t)(c0 + cs * 16 + r) * NPIX + ks * 32 + g * 8];

  #pragma unroll 2
  for (int t = 0; t < 64; ++t) {
    const int cur = t & 1;
    const f32x4 z = {0.f, 0.f, 0.f, 0.f};

    // S^T tile: D rows = j (w*16+4g+e), cols = i (is*16+r)
    f32x4 s[4];
    #pragma unroll
    for (int is = 0; is < 4; ++is) s[is] = mfma16(kf, qf[is], z);

    // prefetch next tile (in flight across the barrier)
    const int jn = ((t + 1) & 63) * 64;
    const s16x8 nkf = *(const s16x8*)&Kbase[(size_t)(jn + w * 16 + r) * CQD + g * 8];
    s16x8 nvf[2][2];
    #pragma unroll
    for (int cs = 0; cs < 2; ++cs)
      #pragma unroll
      for (int ks = 0; ks < 2; ++ks)
        nvf[cs][ks] = *(const s16x8*)&Vbase[(size_t)(c0 + cs * 16 + r) * NPIX + jn + ks * 32 + g * 8];

    // P = exp2(S) -> packed bf16 -> one b64 LDS write per i-sub
    #pragma unroll
    for (int is = 0; is < 4; ++is) {
      const float p0v = fexp2(s[is][0]);
      const float p1v = fexp2(s[is][1]);
      const float p2v = fexp2(s[is][2]);
      const float p3v = fexp2(s[is][3]);
      uint2 pk;
      pk.x = cvt_pk_bf16(p0v, p1v);
      pk.y = cvt_pk_bf16(p2v, p3v);
      *(uint2*)&Ps[cur][is * 16 + r][w * 16 + 4 * g] = pk;
    }

    __syncthreads();

    // PV: O[ch][i] += V[ch][j] P^T[j][i]
    #pragma unroll
    for (int is = 0; is < 4; ++is) {
      const s16x8 pb0 = *(const s16x8*)&Ps[cur][is * 16 + r][g * 8];
      const s16x8 pb1 = *(const s16x8*)&Ps[cur][is * 16 + r][32 + g * 8];
      o[is][0] = mfma16(vf[0][0], pb0, o[is][0]);
      o[is][0] = mfma16(vf[0][1], pb1, o[is][0]);
      o[is][1] = mfma16(vf[1][0], pb0, o[is][1]);
      o[is][1] = mfma16(vf[1][1], pb1, o[is][1]);
      if (is == w) {  // row-sums for i-sub w (all D rows equal)
        o_l = mfma16(ones, pb0, o_l);
        o_l = mfma16(ones, pb1, o_l);
      }
    }

    kf = nkf;
    #pragma unroll
    for (int cs = 0; cs < 2; ++cs)
      #pragma unroll
      for (int ks = 0; ks < 2; ++ks) vf[cs][ks] = nvf[cs][ks];
  }

  // publish l: wave w holds l for i = w*16 + r (cols), any row elem
  if (g == 0) l_s[w * 16 + r] = o_l[0];
  __syncthreads();

  float rl[4];
  #pragma unroll
  for (int is = 0; is < 4; ++is) rl[is] = frcp(l_s[is * 16 + r]);

  const float gam = gamma[0];
  #pragma unroll
  for (int is = 0; is < 4; ++is)
    #pragma unroll
    for (int cs = 0; cs < 2; ++cs)
      #pragma unroll
      for (int e = 0; e < 4; ++e) {
        const int ch = c0 + cs * 16 + 4 * g + e;
        const size_t off = ((size_t)b * CH + ch) * NPIX + i0 + is * 16 + r;
        out[off] = gam * o[is][cs][e] * rl[is] + x[off];
      }
}

extern "C" void kernel_launch(void* const* d_in, const int* in_sizes, int n_in,
                              void* d_out, int out_size, void* d_ws, size_t ws_size,
                              hipStream_t stream) {
  const float* x     = (const float*)d_in[0];
  const float* wq    = (const float*)d_in[1];
  const float* bq    = (const float*)d_in[2];
  const float* wk    = (const float*)d_in[3];
  const float* bk    = (const float*)d_in[4];
  const float* wv    = (const float*)d_in[5];
  const float* bv    = (const float*)d_in[6];
  const float* gamma = (const float*)d_in[7];
  float* out = (float*)d_out;

  // ws: Qb 1MB | Kb 1MB | Vb 8MB | Wp 160KB  (~10.2 MB)
  unsigned short* Qb = (unsigned short*)d_ws;
  unsigned short* Kb = Qb + (size_t)4 * NPIX * CQD;
  unsigned short* Vb = Kb + (size_t)4 * NPIX * CQD;
  unsigned short* Wp = Vb + (size_t)4 * CH * NPIX;

  hipLaunchKernelGGL(wpack_kernel, dim3(320), dim3(256), 0, stream, wq, wk, wv, Wp);
  hipLaunchKernelGGL(proj_kernel,  dim3(256), dim3(512), 0, stream,
                     x, Wp, bq, bk, bv, Qb, Kb, Vb);
  hipLaunchKernelGGL(attn_kernel,  dim3(512), dim3(256), 0, stream,
                     Qb, Kb, Vb, x, gamma, out);
}